// Round 7
// baseline (312.615 us; speedup 1.0000x reference)
//
#include <hip/hip_runtime.h>

#define N_ 32
#define C_ 512
#define T_ 2048
#define H_ 2
#define K_ 512
#define D_ 256
#define NBINS (K_ * K_)
#define TT 64
#define DELTA 0.6f

typedef __bf16 bf16x8 __attribute__((ext_vector_type(8)));
typedef float f32x4 __attribute__((ext_vector_type(4)));

__device__ __forceinline__ unsigned short f2b(float f) {
    return __builtin_bit_cast(unsigned short, (__bf16)f);
}
__device__ __forceinline__ float bf2f(unsigned bits_lo16) {
    return __builtin_bit_cast(float, bits_lo16 << 16);
}

// ---------------- prep: bf16 codebook + norms (fp32 & bf16-domain) ----------------
__global__ void prep_k(const float* __restrict__ cb, float* __restrict__ cnorm,
                       float* __restrict__ cnb, unsigned short* __restrict__ cbb) {
    const int id = blockIdx.x;      // h*512 + k
    const int lane = threadIdx.x;   // 64
    const float4 v = *(const float4*)(cb + (size_t)id * D_ + lane * 4);
    __bf16 b0 = (__bf16)v.x, b1 = (__bf16)v.y, b2 = (__bf16)v.z, b3 = (__bf16)v.w;
    ushort4 uu;
    uu.x = __builtin_bit_cast(unsigned short, b0);
    uu.y = __builtin_bit_cast(unsigned short, b1);
    uu.z = __builtin_bit_cast(unsigned short, b2);
    uu.w = __builtin_bit_cast(unsigned short, b3);
    *(ushort4*)(cbb + (size_t)id * D_ + lane * 4) = uu;
    float f0 = (float)b0, f1 = (float)b1, f2 = (float)b2, f3 = (float)b3;
    float s32 = v.x * v.x + v.y * v.y + v.z * v.z + v.w * v.w;
    float sbb = f0 * f0 + f1 * f1 + f2 * f2 + f3 * f3;
    #pragma unroll
    for (int m = 1; m <= 32; m <<= 1) {
        s32 += __shfl_xor(s32, m, 64);
        sbb += __shfl_xor(sbb, m, 64);
    }
    if (lane == 0) { cnorm[id] = s32; cnb[id] = sbb; }
}

// ---------------- main: MFMA distances + guarded exact argmin + gather/loss ----------------
// LDS overlay (37,968 B; 4 blocks/CU with VGPR<=128):
//   [0, 33280)   phase 1: xstage 64t x 512B (swizzled bf16 x-tile)
//                phase 2: cbs codebook dbuf 2 x 16 KB (swizzled)
//                phase 3: win 32 rows x 260 f32 (epilogue)
//   [33280, 37376)  xrw: 4 waves x 256 f32 rescue row
//   [37376, 37632)  idx_sh[64]
//   [37632, 37648)  wred[4]
//   [37648, 37968)  rl[4][20]
// NOTES: (256,4) caps VGPR at 64 -> d2s spills (R5: 3x slower). Keeping au[8]
// live past the chunk loop also spills (R6: +78MB scratch traffic) — commit
// loss is therefore computed as ||x~||^2 + m1 (no epilogue x read needed).
__global__ __launch_bounds__(256, 2) void vq_main(
    const float* __restrict__ x, const float* __restrict__ cbf,
    const float* __restrict__ cnorm, const float* __restrict__ cnb,
    const unsigned short* __restrict__ cbb,
    float* __restrict__ out, int* __restrict__ idx_ws, float* __restrict__ commit)
{
    __shared__ __align__(16) unsigned char SM[37968];
    unsigned char*  xstage = SM;
    unsigned char*  cbs    = SM;
    float* win    = (float*)SM;
    float* xrw    = (float*)(SM + 33280);
    int*   idx_sh = (int*)(SM + 37376);
    float* wred   = (float*)(SM + 37632);
    int*   rl     = (int*)(SM + 37648);

    const int tid = threadIdx.x;
    const int lane = tid & 63;
    const int w = tid >> 6;
    const int n = blockIdx.y, h = blockIdx.z;
    const int t0 = blockIdx.x * TT;
    const size_t xbase = (size_t)n * C_ * T_ + (size_t)h * D_ * T_;

    // ---- issue codebook chunk 0 loads (reg staging) ----
    const uint4* cbb4 = (const uint4*)(cbb + (size_t)(h * K_) * D_);
    uint4 creg[4];
    {
        const int sb0 = w * 4096 + lane * 16;
        #pragma unroll
        for (int it = 0; it < 4; ++it)
            creg[it] = cbb4[(sb0 + it * 1024) >> 4];
    }

    // ---- transpose-stage x tile -> xstage (bf16, swizzled); accumulate ||x~||^2 ----
    float psum = 0.f;   // this thread's slice of sum over rows of ||x~||^2
    {
        const int tq = lane & 15, dl = lane >> 4;
        const float* xp = x + xbase + (size_t)(w * 64 + dl) * T_ + t0 + 4 * tq;
        const int t = 4 * tq + dl;
        #pragma unroll
        for (int i = 0; i < 16; ++i) {
            float4 v = *(const float4*)(xp + (size_t)(4 * i) * T_);
            float a0 = v.x, a1 = v.y, a2 = v.z, a3 = v.w;
            { float s = (lane & 16) ? a0 : a1; s = __shfl_xor(s, 16, 64); if (lane & 16) a0 = s; else a1 = s; }
            { float s = (lane & 16) ? a2 : a3; s = __shfl_xor(s, 16, 64); if (lane & 16) a2 = s; else a3 = s; }
            { float s = (lane & 32) ? a0 : a2; s = __shfl_xor(s, 32, 64); if (lane & 32) a0 = s; else a2 = s; }
            { float s = (lane & 32) ? a1 : a3; s = __shfl_xor(s, 32, 64); if (lane & 32) a1 = s; else a3 = s; }
            uint2 pk;
            pk.x = (unsigned)f2b(a0) | ((unsigned)f2b(a1) << 16);
            pk.y = (unsigned)f2b(a2) | ((unsigned)f2b(a3) << 16);
            const float r0 = bf2f(pk.x & 0xffffu), r1 = bf2f(pk.x >> 16);
            const float r2 = bf2f(pk.y & 0xffffu), r3 = bf2f(pk.y >> 16);
            psum += r0 * r0 + r1 * r1 + r2 * r2 + r3 * r3;
            const int off = (w * 64 + 4 * i) * 2;
            *(uint2*)(xstage + t * 512 + (off ^ ((t & 7) << 4))) = pk;
        }
    }
    __syncthreads();

    // ---- A fragments (this wave's 16 t rows) ----
    uint4 au[8];
    const int tA = 16 * w + (lane & 15);
    const int koff = (lane >> 4) * 16;     // BYTE offset of k-slice (g*16 B = 8 dims)
    #pragma unroll
    for (int kt = 0; kt < 8; ++kt) {
        const int off = kt * 64 + koff;
        au[kt] = *(const uint4*)(xstage + tA * 512 + (off ^ ((tA & 7) << 4)));
    }
    __syncthreads();   // all waves have x in regs; xstage region now reusable as cbs

    // ---- write codebook chunk 0 into LDS (swizzled) ----
    #pragma unroll
    for (int it = 0; it < 4; ++it) {
        const int sb = w * 4096 + it * 1024 + lane * 16;
        const int code = sb >> 9, off = sb & 511;
        *(uint4*)(cbs + code * 512 + (off ^ ((code & 7) << 4))) = creg[it];
    }
    __syncthreads();

    // ---- chunk loop: 16 chunks x 32 codes ----
    float m1[4], m2[4]; int k1[4];
    #pragma unroll
    for (int q = 0; q < 4; ++q) { m1[q] = 3e38f; m2[q] = 3e38f; k1[q] = 0; }
    unsigned d2s[32][2];
    const int col = lane & 15;

    #pragma unroll
    for (int kc = 0; kc < 16; ++kc) {
        const int buf = (kc & 1) * 16384;
        if (kc < 15) {
            const int sb0 = w * 4096 + lane * 16;
            #pragma unroll
            for (int it = 0; it < 4; ++it)
                creg[it] = cbb4[((kc + 1) * 16384 + sb0 + it * 1024) >> 4];
        }
        const float cn0 = cnb[h * K_ + kc * 32 + col];
        const float cn1 = cnb[h * K_ + kc * 32 + 16 + col];

        #pragma unroll
        for (int sub = 0; sub < 2; ++sub) {
            const int c32 = sub * 16 + col;
            f32x4 acc = {0.f, 0.f, 0.f, 0.f};
            #pragma unroll
            for (int kt = 0; kt < 8; ++kt) {
                uint4 bu = *(const uint4*)(cbs + buf + c32 * 512 + ((kt * 64 + koff) ^ ((c32 & 7) << 4)));
                acc = __builtin_amdgcn_mfma_f32_16x16x32_bf16(
                        __builtin_bit_cast(bf16x8, au[kt]),
                        __builtin_bit_cast(bf16x8, bu), acc, 0, 0, 0);
            }
            const float cn = sub ? cn1 : cn0;
            const int code = kc * 32 + sub * 16 + col;
            float d2q[4];
            #pragma unroll
            for (int q = 0; q < 4; ++q) {
                const float d = fmaf(-2.f, acc[q], cn);
                d2q[q] = d;
                const float mx = fmaxf(d, m1[q]);
                m2[q] = fminf(m2[q], mx);
                const bool lt = d < m1[q];
                k1[q] = lt ? code : k1[q];
                m1[q] = lt ? d : m1[q];
            }
            d2s[kc * 2 + sub][0] = (unsigned)f2b(d2q[0]) | ((unsigned)f2b(d2q[1]) << 16);
            d2s[kc * 2 + sub][1] = (unsigned)f2b(d2q[2]) | ((unsigned)f2b(d2q[3]) << 16);
        }
        if (kc < 15) {
            #pragma unroll
            for (int it = 0; it < 4; ++it) {
                const int sb = w * 4096 + it * 1024 + lane * 16;
                const int code = sb >> 9, off = sb & 511;
                *(uint4*)(cbs + (buf ^ 16384) + code * 512 + (off ^ ((code & 7) << 4))) = creg[it];
            }
        }
        __syncthreads();
    }

    // ---- cross-lane (16 cols) lexicographic argmin + global 2nd-min ----
    #pragma unroll
    for (int m = 1; m <= 8; m <<= 1) {
        #pragma unroll
        for (int q = 0; q < 4; ++q) {
            const float om1 = __shfl_xor(m1[q], m, 64);
            const int   ok  = __shfl_xor(k1[q], m, 64);
            const float om2 = __shfl_xor(m2[q], m, 64);
            const float nm2 = fminf(fminf(m2[q], om2), fmaxf(m1[q], om1));
            const bool sw = (om1 < m1[q]) || (om1 == m1[q] && ok < k1[q]);
            m1[q] = sw ? om1 : m1[q];
            k1[q] = sw ? ok : k1[q];
            m2[q] = nm2;
        }
    }

    if (lane == 0) rl[w * 20] = 0;
    const int g = lane >> 4;

    // ---- guarded exact rescore (rare) ----
    #pragma unroll
    for (int gg = 0; gg < 4; ++gg) {
        #pragma unroll
        for (int q = 0; q < 4; ++q) {
            const float bm1 = __shfl(m1[q], gg << 4, 64);
            const float bm2 = __shfl(m2[q], gg << 4, 64);
            if (bm2 < bm1 + DELTA) {
                const int row = 16 * w + 4 * gg + q;
                const float* xc = x + xbase + t0 + row;
                float4 xr;
                xr.x = xc[(size_t)(lane * 4 + 0) * T_];
                xr.y = xc[(size_t)(lane * 4 + 1) * T_];
                xr.z = xc[(size_t)(lane * 4 + 2) * T_];
                xr.w = xc[(size_t)(lane * 4 + 3) * T_];
                *(float4*)&xrw[w * 256 + lane * 4] = xr;
                if (g == gg) {
                    const float thrw = bm1 + (DELTA + 1.5f);
                    #pragma unroll
                    for (int i = 0; i < 32; ++i) {
                        const unsigned uu = d2s[i][q >> 1];
                        const float s = (q & 1) ? __builtin_bit_cast(float, uu & 0xffff0000u)
                                                : __builtin_bit_cast(float, uu << 16);
                        if (s < thrw) {
                            const int pos = atomicAdd(&rl[w * 20], 1);
                            if (pos < 19) rl[w * 20 + 1 + pos] = i * 16 + col;
                        }
                    }
                }
                __asm__ volatile("s_waitcnt lgkmcnt(0)" ::: "memory");
                int nc = rl[w * 20];
                if (nc > 19) nc = 19;
                float bv = 3e38f; int bk = 0x7fffffff;
                for (int ci = 0; ci < nc; ++ci) {
                    const int code = rl[w * 20 + 1 + ci];
                    const float4 xv = *(const float4*)&xrw[w * 256 + lane * 4];
                    const float4 cv = *(const float4*)&cbf[(size_t)(h * K_ + code) * D_ + lane * 4];
                    float d = xv.x * cv.x + xv.y * cv.y + xv.z * cv.z + xv.w * cv.w;
                    #pragma unroll
                    for (int mm = 1; mm <= 32; mm <<= 1) d += __shfl_xor(d, mm, 64);
                    const float d2x = cnorm[h * K_ + code] - 2.f * d;
                    if (d2x < bv || (d2x == bv && code < bk)) { bv = d2x; bk = code; }
                }
                if (g == gg) { k1[q] = bk; m1[q] = bv; }
                if (lane == 0) rl[w * 20] = 0;
            }
        }
    }

    // ---- write indices ----
    if ((lane & 15) == 0) {
        #pragma unroll
        for (int q = 0; q < 4; ++q) {
            const int row = 16 * w + 4 * g + q;
            idx_sh[row] = k1[q];
            idx_ws[((size_t)n * T_ + t0 + row) * H_ + h] = k1[q];
        }
    }
    __syncthreads();

    // ---- commit loss: sum over rows of ||x~||^2 + m1  (no epilogue x read) ----
    float csum = psum;
    if (col == 0) csum += m1[0] + m1[1] + m1[2] + m1[3];

    // ---- epilogue: gather winners via win LDS; coalesced out write ----
    #pragma unroll
    for (int ch = 0; ch < 2; ++ch) {
        #pragma unroll
        for (int rr = 0; rr < 8; ++rr) {
            const int row = ch * 32 + w * 8 + rr;
            const int code = idx_sh[row];
            const float4 cv = *(const float4*)&cbf[(size_t)(h * K_ + code) * D_ + lane * 4];
            *(float4*)&win[(row & 31) * 260 + lane * 4] = cv;
        }
        __syncthreads();
        const int t32 = tid & 31, cg = tid >> 5;
        float* op = out + (size_t)n * C_ * T_ + (size_t)h * D_ * T_ + t0 + ch * 32 + t32;
        #pragma unroll
        for (int i = 0; i < 32; ++i) {
            const int c = cg + 8 * i;
            op[(size_t)c * T_] = win[t32 * 260 + c];
        }
        __syncthreads();
    }
    #pragma unroll
    for (int mm = 1; mm <= 32; mm <<= 1) csum += __shfl_xor(csum, mm, 64);
    if (lane == 0) wred[w] = csum;
    __syncthreads();
    if (tid == 0) atomicAdd(commit, wred[0] + wred[1] + wred[2] + wred[3]);
}

// ---------------- histogram ----------------
__global__ void hist_k(const int* __restrict__ idx_ws, int* __restrict__ counts) {
    const int gid = blockIdx.x * 256 + threadIdx.x;
    const int i0 = idx_ws[(size_t)gid * H_ + 0];
    const int i1 = idx_ws[(size_t)gid * H_ + 1];
    atomicAdd(&counts[i0 + K_ * i1], 1);
}

// ---------------- entropy: 256 blocks x 256 threads x int4 ----------------
__global__ __launch_bounds__(256) void entropy_k(const int* __restrict__ counts,
                                                 float* __restrict__ ent) {
    __shared__ float red[4];
    const int tid = threadIdx.x;
    const int4 c4 = *(const int4*)(counts + 4 * (blockIdx.x * 256 + tid));
    float s = 0.f;
    {
        const float p0 = (float)c4.x * (1.f / 65536.f);
        const float p1 = (float)c4.y * (1.f / 65536.f);
        const float p2 = (float)c4.z * (1.f / 65536.f);
        const float p3 = (float)c4.w * (1.f / 65536.f);
        s = p0 * logf(p0 + 1e-7f) + p1 * logf(p1 + 1e-7f)
          + p2 * logf(p2 + 1e-7f) + p3 * logf(p3 + 1e-7f);
    }
    #pragma unroll
    for (int m = 1; m <= 32; m <<= 1) s += __shfl_xor(s, m, 64);
    if ((tid & 63) == 0) red[tid >> 6] = s;
    __syncthreads();
    if (tid == 0) atomicAdd(ent, red[0] + red[1] + red[2] + red[3]);
}

// ---------------- scalars ----------------
__global__ void final_k(const float* __restrict__ ent,
                        const float* __restrict__ commit,
                        float* __restrict__ outsc) {
    if (threadIdx.x == 0) {
        outsc[0] = commit[0] * (1.f / 33554432.f);
        outsc[1] = expf(-ent[0]);
    }
}

extern "C" void kernel_launch(void* const* d_in, const int* in_sizes, int n_in,
                              void* d_out, int out_size, void* d_ws, size_t ws_size,
                              hipStream_t stream) {
    const float* x  = (const float*)d_in[0];   // [32, 512, 2048]
    const float* cb = (const float*)d_in[1];   // [2, 512, 256]
    float* out = (float*)d_out;

    char* ws = (char*)d_ws;
    int*   counts = (int*)ws;                              // 1 MB
    float* commit = (float*)(ws + 1048576);
    float* ent    = (float*)(ws + 1048580);
    float* cnorm  = (float*)(ws + 1048832);                // 1024 f32
    float* cnb    = (float*)(ws + 1052928);                // 1024 f32
    unsigned short* cbb = (unsigned short*)(ws + 1057024); // 512 KB bf16 codebook
    int*   idx_ws = (int*)(ws + 1581312);                  // 512 KB

    hipMemsetAsync(d_ws, 0, 1048832, stream);
    prep_k<<<H_ * K_, 64, 0, stream>>>(cb, cnorm, cnb, cbb);
    vq_main<<<dim3(T_ / TT, N_, H_), 256, 0, stream>>>(x, cb, cnorm, cnb, cbb, out, idx_ws, commit);
    hist_k<<<N_ * T_ / 256, 256, 0, stream>>>(idx_ws, counts);
    entropy_k<<<NBINS / 1024, 256, 0, stream>>>(counts, ent);
    final_k<<<1, 64, 0, stream>>>(ent, commit, out + 33554432);
}

// Round 8
// 171.542 us; speedup vs baseline: 1.8224x; 1.8224x over previous
//
#include <hip/hip_runtime.h>

#define N_ 32
#define C_ 512
#define T_ 2048
#define H_ 2
#define K_ 512
#define D_ 256
#define NBINS (K_ * K_)
#define TT 64
#define DELTA 0.6f

typedef __bf16 bf16x8 __attribute__((ext_vector_type(8)));
typedef float f32x4 __attribute__((ext_vector_type(4)));

__device__ __forceinline__ unsigned short f2b(float f) {
    return __builtin_bit_cast(unsigned short, (__bf16)f);
}
__device__ __forceinline__ float bf2f(unsigned bits_lo16) {
    return __builtin_bit_cast(float, bits_lo16 << 16);
}
// async global->LDS DMA, 16B/lane: LDS dest = wave-uniform base + lane*16 (linear);
// the swizzle lives in the PRE-PERMUTED global source (rule 21 / m173 pattern).
__device__ __forceinline__ void gl_lds16(const void* g, void* l) {
    __builtin_amdgcn_global_load_lds(
        (const __attribute__((address_space(1))) void*)g,
        (__attribute__((address_space(3))) void*)l, 16, 0, 0);
}

// ---------------- prep: PRE-SWIZZLED bf16 codebook + norms (fp32 & bf16-domain) ----
// cbb layout: per head, 16 chunks of 16KB (32 codes). Within a chunk, byte L holds
// orig byte g(L) = (L>>9)*512 + ((L&511) ^ (((L>>9)&7)<<4)), so a LINEAR
// global->LDS copy produces the swizzled cbs layout the MFMA B-reads expect.
__global__ void prep_k(const float* __restrict__ cb, float* __restrict__ cnorm,
                       float* __restrict__ cnb, unsigned short* __restrict__ cbb) {
    const int id = blockIdx.x;      // h*512 + k
    const int lane = threadIdx.x;   // 64
    const int h = id >> 9, k = id & 511;
    const float4 v = *(const float4*)(cb + (size_t)id * D_ + lane * 4);
    __bf16 b0 = (__bf16)v.x, b1 = (__bf16)v.y, b2 = (__bf16)v.z, b3 = (__bf16)v.w;
    ushort4 uu;
    uu.x = __builtin_bit_cast(unsigned short, b0);
    uu.y = __builtin_bit_cast(unsigned short, b1);
    uu.z = __builtin_bit_cast(unsigned short, b2);
    uu.w = __builtin_bit_cast(unsigned short, b3);
    {
        const int c = k & 31;                       // code within chunk
        const size_t dst = (size_t)h * 262144 + (size_t)(k >> 5) * 16384
                         + (size_t)c * 512
                         + ((((lane >> 1) << 4) ^ ((c & 7) << 4)) + (lane & 1) * 8);
        *(ushort4*)((unsigned char*)cbb + dst) = uu;
    }
    float f0 = (float)b0, f1 = (float)b1, f2 = (float)b2, f3 = (float)b3;
    float s32 = v.x * v.x + v.y * v.y + v.z * v.z + v.w * v.w;
    float sbb = f0 * f0 + f1 * f1 + f2 * f2 + f3 * f3;
    #pragma unroll
    for (int m = 1; m <= 32; m <<= 1) {
        s32 += __shfl_xor(s32, m, 64);
        sbb += __shfl_xor(sbb, m, 64);
    }
    if (lane == 0) { cnorm[id] = s32; cnb[id] = sbb; }
}

// ---------------- main: MFMA distances + guarded exact argmin + gather/loss ----------------
// LDS overlay (38,992 B; 4 blocks/CU with VGPR<=128):
//   [0, 33280)   phase 1: xstage 64t x 512B (swizzled bf16 x-tile)
//                phase 2: cbs codebook dbuf 2 x 16 KB (DMA, linear dest)
//                phase 3: win 32 rows x 260 f32 (epilogue)
//   [33280, 37376)  xrw: 4 waves x 256 f32 rescue row
//   [37376, 37632)  idx_sh[64]
//   [37632, 37648)  wred[4]
//   [37648, 37968)  rl[4][20]
//   [37968, 38992)  psum_sh[256] (per-thread ||x~||^2 parked across the loop)
// NOTES: (256,4) caps VGPR at 64 -> d2s spills (R5, 3x slower). R6/R7: allocator
// is at the 128-VGPR cliff — even +1 live reg across the chunk loop spills into
// the hot loop. Fix: creg[4] staging replaced by global_load_lds (16 regs freed),
// psum parked in LDS.
__global__ __launch_bounds__(256, 2) void vq_main(
    const float* __restrict__ x, const float* __restrict__ cbf,
    const float* __restrict__ cnorm, const float* __restrict__ cnb,
    const unsigned short* __restrict__ cbb,
    float* __restrict__ out, int* __restrict__ idx_ws, float* __restrict__ commit)
{
    __shared__ __align__(16) unsigned char SM[38992];
    unsigned char*  xstage = SM;
    unsigned char*  cbs    = SM;
    float* win     = (float*)SM;
    float* xrw     = (float*)(SM + 33280);
    int*   idx_sh  = (int*)(SM + 37376);
    float* wred    = (float*)(SM + 37632);
    int*   rl      = (int*)(SM + 37648);
    float* psum_sh = (float*)(SM + 37968);

    const int tid = threadIdx.x;
    const int lane = tid & 63;
    const int w = tid >> 6;
    const int n = blockIdx.y, h = blockIdx.z;
    const int t0 = blockIdx.x * TT;
    const size_t xbase = (size_t)n * C_ * T_ + (size_t)h * D_ * T_;
    const unsigned char* cbbB = (const unsigned char*)cbb + (size_t)h * 262144;

    // ---- transpose-stage x tile -> xstage (bf16, swizzled); accumulate ||x~||^2 ----
    {
        float psum = 0.f;
        const int tq = lane & 15, dl = lane >> 4;
        const float* xp = x + xbase + (size_t)(w * 64 + dl) * T_ + t0 + 4 * tq;
        const int t = 4 * tq + dl;
        #pragma unroll
        for (int i = 0; i < 16; ++i) {
            float4 v = *(const float4*)(xp + (size_t)(4 * i) * T_);
            float a0 = v.x, a1 = v.y, a2 = v.z, a3 = v.w;
            { float s = (lane & 16) ? a0 : a1; s = __shfl_xor(s, 16, 64); if (lane & 16) a0 = s; else a1 = s; }
            { float s = (lane & 16) ? a2 : a3; s = __shfl_xor(s, 16, 64); if (lane & 16) a2 = s; else a3 = s; }
            { float s = (lane & 32) ? a0 : a2; s = __shfl_xor(s, 32, 64); if (lane & 32) a0 = s; else a2 = s; }
            { float s = (lane & 32) ? a1 : a3; s = __shfl_xor(s, 32, 64); if (lane & 32) a1 = s; else a3 = s; }
            uint2 pk;
            pk.x = (unsigned)f2b(a0) | ((unsigned)f2b(a1) << 16);
            pk.y = (unsigned)f2b(a2) | ((unsigned)f2b(a3) << 16);
            const float r0 = bf2f(pk.x & 0xffffu), r1 = bf2f(pk.x >> 16);
            const float r2 = bf2f(pk.y & 0xffffu), r3 = bf2f(pk.y >> 16);
            psum += r0 * r0 + r1 * r1 + r2 * r2 + r3 * r3;
            const int off = (w * 64 + 4 * i) * 2;
            *(uint2*)(xstage + t * 512 + (off ^ ((t & 7) << 4))) = pk;
        }
        psum_sh[tid] = psum;   // park; re-read in epilogue (keeps it out of the VGPR live set)
    }
    __syncthreads();

    // ---- A fragments (this wave's 16 t rows) ----
    uint4 au[8];
    const int tA = 16 * w + (lane & 15);
    const int koff = (lane >> 4) * 16;     // BYTE offset of k-slice (g*16 B = 8 dims)
    #pragma unroll
    for (int kt = 0; kt < 8; ++kt) {
        const int off = kt * 64 + koff;
        au[kt] = *(const uint4*)(xstage + tA * 512 + (off ^ ((tA & 7) << 4)));
    }
    __syncthreads();   // all waves have x in regs; xstage region now reusable as cbs

    // ---- DMA codebook chunk 0 into LDS (pre-swizzled source, linear dest) ----
    #pragma unroll
    for (int it = 0; it < 4; ++it)
        gl_lds16(cbbB + w * 4096 + it * 1024 + lane * 16,
                 cbs + w * 4096 + it * 1024);
    __syncthreads();   // drains vmcnt -> chunk 0 resident

    // ---- chunk loop: 16 chunks x 32 codes ----
    float m1[4], m2[4]; int k1[4];
    #pragma unroll
    for (int q = 0; q < 4; ++q) { m1[q] = 3e38f; m2[q] = 3e38f; k1[q] = 0; }
    unsigned d2s[32][2];
    const int col = lane & 15;

    #pragma unroll
    for (int kc = 0; kc < 16; ++kc) {
        const int buf = (kc & 1) * 16384;
        if (kc < 15) {   // prefetch next chunk into the other buffer (async DMA)
            #pragma unroll
            for (int it = 0; it < 4; ++it)
                gl_lds16(cbbB + (kc + 1) * 16384 + w * 4096 + it * 1024 + lane * 16,
                         cbs + (buf ^ 16384) + w * 4096 + it * 1024);
        }
        const float cn0 = cnb[h * K_ + kc * 32 + col];
        const float cn1 = cnb[h * K_ + kc * 32 + 16 + col];

        #pragma unroll
        for (int sub = 0; sub < 2; ++sub) {
            const int c32 = sub * 16 + col;
            f32x4 acc = {0.f, 0.f, 0.f, 0.f};
            #pragma unroll
            for (int kt = 0; kt < 8; ++kt) {
                uint4 bu = *(const uint4*)(cbs + buf + c32 * 512 + ((kt * 64 + koff) ^ ((c32 & 7) << 4)));
                acc = __builtin_amdgcn_mfma_f32_16x16x32_bf16(
                        __builtin_bit_cast(bf16x8, au[kt]),
                        __builtin_bit_cast(bf16x8, bu), acc, 0, 0, 0);
            }
            const float cn = sub ? cn1 : cn0;
            const int code = kc * 32 + sub * 16 + col;
            float d2q[4];
            #pragma unroll
            for (int q = 0; q < 4; ++q) {
                const float d = fmaf(-2.f, acc[q], cn);
                d2q[q] = d;
                const float mx = fmaxf(d, m1[q]);
                m2[q] = fminf(m2[q], mx);
                const bool lt = d < m1[q];
                k1[q] = lt ? code : k1[q];
                m1[q] = lt ? d : m1[q];
            }
            d2s[kc * 2 + sub][0] = (unsigned)f2b(d2q[0]) | ((unsigned)f2b(d2q[1]) << 16);
            d2s[kc * 2 + sub][1] = (unsigned)f2b(d2q[2]) | ((unsigned)f2b(d2q[3]) << 16);
        }
        __syncthreads();   // drains DMA (vmcnt) + LDS reads; safe to flip buffers
    }

    // ---- cross-lane (16 cols) lexicographic argmin + global 2nd-min ----
    #pragma unroll
    for (int m = 1; m <= 8; m <<= 1) {
        #pragma unroll
        for (int q = 0; q < 4; ++q) {
            const float om1 = __shfl_xor(m1[q], m, 64);
            const int   ok  = __shfl_xor(k1[q], m, 64);
            const float om2 = __shfl_xor(m2[q], m, 64);
            const float nm2 = fminf(fminf(m2[q], om2), fmaxf(m1[q], om1));
            const bool sw = (om1 < m1[q]) || (om1 == m1[q] && ok < k1[q]);
            m1[q] = sw ? om1 : m1[q];
            k1[q] = sw ? ok : k1[q];
            m2[q] = nm2;
        }
    }

    if (lane == 0) rl[w * 20] = 0;
    const int g = lane >> 4;

    // ---- guarded exact rescore (rare) ----
    #pragma unroll
    for (int gg = 0; gg < 4; ++gg) {
        #pragma unroll
        for (int q = 0; q < 4; ++q) {
            const float bm1 = __shfl(m1[q], gg << 4, 64);
            const float bm2 = __shfl(m2[q], gg << 4, 64);
            if (bm2 < bm1 + DELTA) {
                const int row = 16 * w + 4 * gg + q;
                const float* xc = x + xbase + t0 + row;
                float4 xr;
                xr.x = xc[(size_t)(lane * 4 + 0) * T_];
                xr.y = xc[(size_t)(lane * 4 + 1) * T_];
                xr.z = xc[(size_t)(lane * 4 + 2) * T_];
                xr.w = xc[(size_t)(lane * 4 + 3) * T_];
                *(float4*)&xrw[w * 256 + lane * 4] = xr;
                if (g == gg) {
                    const float thrw = bm1 + (DELTA + 1.5f);
                    #pragma unroll
                    for (int i = 0; i < 32; ++i) {
                        const unsigned uu = d2s[i][q >> 1];
                        const float s = (q & 1) ? __builtin_bit_cast(float, uu & 0xffff0000u)
                                                : __builtin_bit_cast(float, uu << 16);
                        if (s < thrw) {
                            const int pos = atomicAdd(&rl[w * 20], 1);
                            if (pos < 19) rl[w * 20 + 1 + pos] = i * 16 + col;
                        }
                    }
                }
                __asm__ volatile("s_waitcnt lgkmcnt(0)" ::: "memory");
                int nc = rl[w * 20];
                if (nc > 19) nc = 19;
                float bv = 3e38f; int bk = 0x7fffffff;
                for (int ci = 0; ci < nc; ++ci) {
                    const int code = rl[w * 20 + 1 + ci];
                    const float4 xv = *(const float4*)&xrw[w * 256 + lane * 4];
                    const float4 cv = *(const float4*)&cbf[(size_t)(h * K_ + code) * D_ + lane * 4];
                    float d = xv.x * cv.x + xv.y * cv.y + xv.z * cv.z + xv.w * cv.w;
                    #pragma unroll
                    for (int mm = 1; mm <= 32; mm <<= 1) d += __shfl_xor(d, mm, 64);
                    const float d2x = cnorm[h * K_ + code] - 2.f * d;
                    if (d2x < bv || (d2x == bv && code < bk)) { bv = d2x; bk = code; }
                }
                if (g == gg) { k1[q] = bk; m1[q] = bv; }
                if (lane == 0) rl[w * 20] = 0;
            }
        }
    }

    // ---- write indices ----
    if ((lane & 15) == 0) {
        #pragma unroll
        for (int q = 0; q < 4; ++q) {
            const int row = 16 * w + 4 * g + q;
            idx_sh[row] = k1[q];
            idx_ws[((size_t)n * T_ + t0 + row) * H_ + h] = k1[q];
        }
    }
    __syncthreads();

    // ---- commit loss: sum over rows of ||x~||^2 + m1  (no epilogue x read) ----
    float csum = psum_sh[tid];
    if (col == 0) csum += m1[0] + m1[1] + m1[2] + m1[3];

    // ---- epilogue: gather winners via win LDS; coalesced out write ----
    #pragma unroll
    for (int ch = 0; ch < 2; ++ch) {
        #pragma unroll
        for (int rr = 0; rr < 8; ++rr) {
            const int row = ch * 32 + w * 8 + rr;
            const int code = idx_sh[row];
            const float4 cv = *(const float4*)&cbf[(size_t)(h * K_ + code) * D_ + lane * 4];
            *(float4*)&win[(row & 31) * 260 + lane * 4] = cv;
        }
        __syncthreads();
        const int t32 = tid & 31, cg = tid >> 5;
        float* op = out + (size_t)n * C_ * T_ + (size_t)h * D_ * T_ + t0 + ch * 32 + t32;
        #pragma unroll
        for (int i = 0; i < 32; ++i) {
            const int c = cg + 8 * i;
            op[(size_t)c * T_] = win[t32 * 260 + c];
        }
        __syncthreads();
    }
    #pragma unroll
    for (int mm = 1; mm <= 32; mm <<= 1) csum += __shfl_xor(csum, mm, 64);
    if (lane == 0) wred[w] = csum;
    __syncthreads();
    if (tid == 0) atomicAdd(commit, wred[0] + wred[1] + wred[2] + wred[3]);
}

// ---------------- histogram ----------------
__global__ void hist_k(const int* __restrict__ idx_ws, int* __restrict__ counts) {
    const int gid = blockIdx.x * 256 + threadIdx.x;
    const int i0 = idx_ws[(size_t)gid * H_ + 0];
    const int i1 = idx_ws[(size_t)gid * H_ + 1];
    atomicAdd(&counts[i0 + K_ * i1], 1);
}

// ---------------- entropy: 256 blocks x 256 threads x int4 ----------------
__global__ __launch_bounds__(256) void entropy_k(const int* __restrict__ counts,
                                                 float* __restrict__ ent) {
    __shared__ float red[4];
    const int tid = threadIdx.x;
    const int4 c4 = *(const int4*)(counts + 4 * (blockIdx.x * 256 + tid));
    float s = 0.f;
    {
        const float p0 = (float)c4.x * (1.f / 65536.f);
        const float p1 = (float)c4.y * (1.f / 65536.f);
        const float p2 = (float)c4.z * (1.f / 65536.f);
        const float p3 = (float)c4.w * (1.f / 65536.f);
        s = p0 * logf(p0 + 1e-7f) + p1 * logf(p1 + 1e-7f)
          + p2 * logf(p2 + 1e-7f) + p3 * logf(p3 + 1e-7f);
    }
    #pragma unroll
    for (int m = 1; m <= 32; m <<= 1) s += __shfl_xor(s, m, 64);
    if ((tid & 63) == 0) red[tid >> 6] = s;
    __syncthreads();
    if (tid == 0) atomicAdd(ent, red[0] + red[1] + red[2] + red[3]);
}

// ---------------- scalars ----------------
__global__ void final_k(const float* __restrict__ ent,
                        const float* __restrict__ commit,
                        float* __restrict__ outsc) {
    if (threadIdx.x == 0) {
        outsc[0] = commit[0] * (1.f / 33554432.f);
        outsc[1] = expf(-ent[0]);
    }
}

extern "C" void kernel_launch(void* const* d_in, const int* in_sizes, int n_in,
                              void* d_out, int out_size, void* d_ws, size_t ws_size,
                              hipStream_t stream) {
    const float* x  = (const float*)d_in[0];   // [32, 512, 2048]
    const float* cb = (const float*)d_in[1];   // [2, 512, 256]
    float* out = (float*)d_out;

    char* ws = (char*)d_ws;
    int*   counts = (int*)ws;                              // 1 MB
    float* commit = (float*)(ws + 1048576);
    float* ent    = (float*)(ws + 1048580);
    float* cnorm  = (float*)(ws + 1048832);                // 1024 f32
    float* cnb    = (float*)(ws + 1052928);                // 1024 f32
    unsigned short* cbb = (unsigned short*)(ws + 1057024); // 512 KB pre-swizzled bf16 codebook
    int*   idx_ws = (int*)(ws + 1581312);                  // 512 KB

    hipMemsetAsync(d_ws, 0, 1048832, stream);
    prep_k<<<H_ * K_, 64, 0, stream>>>(cb, cnorm, cnb, cbb);
    vq_main<<<dim3(T_ / TT, N_, H_), 256, 0, stream>>>(x, cb, cnorm, cnb, cbb, out, idx_ws, commit);
    hist_k<<<N_ * T_ / 256, 256, 0, stream>>>(idx_ws, counts);
    entropy_k<<<NBINS / 1024, 256, 0, stream>>>(counts, ent);
    final_k<<<1, 64, 0, stream>>>(ent, commit, out + 33554432);
}